// Round 1
// baseline (1676.650 us; speedup 1.0000x reference)
//
#include <hip/hip_runtime.h>
#include <math.h>

#define N_NODES 50000
#define N_EDGES 800000
#define E_TOT   (N_EDGES + N_NODES)   // 850000, self-loops appended
#define IN_DIM  32
#define HID     96
#define NEG_SLOPE 0.2f

// ---- ordered-uint encoding for float atomicMax; init 0 == "-inf" sentinel ----
__device__ __forceinline__ unsigned f2ord(float f) {
    unsigned u = __float_as_uint(f);
    return (u & 0x80000000u) ? ~u : (u | 0x80000000u);
}
__device__ __forceinline__ float ord2f(unsigned u) {
    return __uint_as_float((u & 0x80000000u) ? (u & 0x7FFFFFFFu) : ~u);
}

// h = x @ W   (thread per node*dout element)
__global__ void gemm_kernel(const float* __restrict__ x, const float* __restrict__ W,
                            float* __restrict__ h, int n, int din, int dout) {
    int idx = blockIdx.x * blockDim.x + threadIdx.x;
    if (idx >= n * dout) return;
    int node = idx / dout;
    int c    = idx - node * dout;
    const float* xr = x + (long long)node * din;
    float acc = 0.f;
    #pragma unroll 8
    for (int k = 0; k < din; ++k) acc += xr[k] * W[k * dout + c];
    h[idx] = acc;
}

// es[i] = h[i,:].a_s ; ed[i] = h[i,:].a_d   (one wave per node)
__global__ void scores_kernel(const float* __restrict__ h, const float* __restrict__ a_s,
                              const float* __restrict__ a_d, float* __restrict__ es,
                              float* __restrict__ ed, int n, int dout) {
    int wave = (blockIdx.x * blockDim.x + threadIdx.x) >> 6;
    int lane = threadIdx.x & 63;
    if (wave >= n) return;
    float ps = 0.f, pd = 0.f;
    for (int c = lane; c < dout; c += 64) {
        float hv = h[(long long)wave * dout + c];
        ps += hv * a_s[c];
        pd += hv * a_d[c];
    }
    #pragma unroll
    for (int o = 32; o > 0; o >>= 1) {
        ps += __shfl_down(ps, o);
        pd += __shfl_down(pd, o);
    }
    if (lane == 0) { es[wave] = ps; ed[wave] = pd; }
}

// per edge: e = leaky(es[src]+ed[dst]); stash; atomicMax into m[dst]
__global__ void edge_max_kernel(const int* __restrict__ ei, const float* __restrict__ es,
                                const float* __restrict__ ed, float* __restrict__ ev,
                                unsigned* __restrict__ m) {
    int e = blockIdx.x * blockDim.x + threadIdx.x;
    if (e >= E_TOT) return;
    int s, d;
    if (e < N_EDGES) { s = ei[e]; d = ei[N_EDGES + e]; }
    else             { s = d = e - N_EDGES; }
    float v = es[s] + ed[d];
    v = (v > 0.f) ? v : NEG_SLOPE * v;
    ev[e] = v;
    atomicMax(m + d, f2ord(v));
}

// per edge: ex = exp(e - m[dst]); stash; atomicAdd into s[dst]
__global__ void edge_sum_kernel(const int* __restrict__ ei, float* __restrict__ ev,
                                const unsigned* __restrict__ m, float* __restrict__ ssum) {
    int e = blockIdx.x * blockDim.x + threadIdx.x;
    if (e >= E_TOT) return;
    int d = (e < N_EDGES) ? ei[N_EDGES + e] : (e - N_EDGES);
    float ex = expf(ev[e] - ord2f(m[d]));
    ev[e] = ex;
    atomicAdd(ssum + d, ex);
}

// per (edge, channel): out[dst,c] += (ex/s[dst]) * h[src,c]
__global__ void edge_acc_kernel(const int* __restrict__ ei, const float* __restrict__ ev,
                                const float* __restrict__ ssum, const float* __restrict__ h,
                                float* __restrict__ out, int dout) {
    int idx = blockIdx.x * blockDim.x + threadIdx.x;
    if (idx >= E_TOT * dout) return;
    int e = idx / dout;
    int c = idx - e * dout;
    int s, d;
    if (e < N_EDGES) { s = ei[e]; d = ei[N_EDGES + e]; }
    else             { s = d = e - N_EDGES; }
    float alpha = ev[e] / ssum[d];
    atomicAdd(out + (long long)d * dout + c, alpha * h[(long long)s * dout + c]);
}

// out = acc + b (+ residual) (relu), in-place capable (acc == out ok)
__global__ void finalize_kernel(const float* __restrict__ acc, const float* __restrict__ b,
                                const float* __restrict__ res, float* __restrict__ out,
                                int n, int dout, int do_relu) {
    int idx = blockIdx.x * blockDim.x + threadIdx.x;
    if (idx >= n * dout) return;
    int c = idx % dout;
    float v = acc[idx] + b[c];
    if (res) v += res[idx];
    if (do_relu) v = fmaxf(v, 0.f);
    out[idx] = v;
}

static inline int cdiv(long long a, int b) { return (int)((a + b - 1) / b); }

// One GAT conv layer: in(n,din) -> writes finalize into accbuf (in-place), returns nothing.
static void run_layer(const float* x_in, const int* ei,
                      const float* W, const float* a_s, const float* a_d, const float* b,
                      float* h, float* es, float* ed, unsigned* m, float* ssum, float* ev,
                      float* acc, const float* residual, float* x_out,
                      int din, int dout, int do_relu, hipStream_t stream) {
    const int n = N_NODES;
    // zero m, ssum (adjacent) and acc
    hipMemsetAsync(m, 0, (size_t)n * sizeof(unsigned), stream);
    hipMemsetAsync(ssum, 0, (size_t)n * sizeof(float), stream);
    hipMemsetAsync(acc, 0, (size_t)n * dout * sizeof(float), stream);

    gemm_kernel<<<cdiv((long long)n * dout, 256), 256, 0, stream>>>(x_in, W, h, n, din, dout);
    scores_kernel<<<cdiv(n, 4), 256, 0, stream>>>(h, a_s, a_d, es, ed, n, dout);
    edge_max_kernel<<<cdiv(E_TOT, 256), 256, 0, stream>>>(ei, es, ed, ev, m);
    edge_sum_kernel<<<cdiv(E_TOT, 256), 256, 0, stream>>>(ei, ev, m, ssum);
    edge_acc_kernel<<<cdiv((long long)E_TOT * dout, 256), 256, 0, stream>>>(ei, ev, ssum, h, acc, dout);
    finalize_kernel<<<cdiv((long long)n * dout, 256), 256, 0, stream>>>(acc, b, residual, x_out, n, dout, do_relu);
}

extern "C" void kernel_launch(void* const* d_in, const int* in_sizes, int n_in,
                              void* d_out, int out_size, void* d_ws, size_t ws_size,
                              hipStream_t stream) {
    const float* x  = (const float*)d_in[0];
    const int*   ei = (const int*)d_in[1];   // [2, N_EDGES] row-major, int32 per harness
    // d_in[2] edge_weight: ignored by reference
    const float* W0 = (const float*)d_in[3];
    const float* as0 = (const float*)d_in[4];
    const float* ad0 = (const float*)d_in[5];
    const float* b0 = (const float*)d_in[6];
    const float* W1 = (const float*)d_in[7];
    const float* as1 = (const float*)d_in[8];
    const float* ad1 = (const float*)d_in[9];
    const float* b1 = (const float*)d_in[10];
    const float* W2 = (const float*)d_in[11];
    const float* as2 = (const float*)d_in[12];
    const float* ad2 = (const float*)d_in[13];
    const float* b2 = (const float*)d_in[14];
    const float* Wf = (const float*)d_in[15];
    const float* asf = (const float*)d_in[16];
    const float* adf = (const float*)d_in[17];
    const float* bf = (const float*)d_in[18];

    float* out = (float*)d_out;  // 50000 floats

    // workspace carve-up (floats)
    float* H  = (float*)d_ws;                 // N*96
    float* FA = H  + (long long)N_NODES * HID; // N*96
    float* FB = FA + (long long)N_NODES * HID; // N*96
    float* ES = FB + (long long)N_NODES * HID; // N
    float* ED = ES + N_NODES;                  // N
    unsigned* M = (unsigned*)(ED + N_NODES);   // N
    float* S  = (float*)M + N_NODES;           // N
    float* EV = S + N_NODES;                   // E_TOT

    // layer 0: x(32) -> FA(96), relu, no residual (shape mismatch)
    run_layer(x,  ei, W0, as0, ad0, b0, H, ES, ED, M, S, EV, FA, nullptr, FA, IN_DIM, HID, 1, stream);
    // layer 1: FA -> FB, residual FA, relu
    run_layer(FA, ei, W1, as1, ad1, b1, H, ES, ED, M, S, EV, FB, FA, FB, HID, HID, 1, stream);
    // layer 2: FB -> FA, residual FB, relu
    run_layer(FB, ei, W2, as2, ad2, b2, H, ES, ED, M, S, EV, FA, FB, FA, HID, HID, 1, stream);
    // final: FA -> out (dout=1), no residual, no relu
    run_layer(FA, ei, Wf, asf, adf, bf, H, ES, ED, M, S, EV, out, nullptr, out, HID, 1, 0, stream);
}

// Round 2
// 627.948 us; speedup vs baseline: 2.6700x; 2.6700x over previous
//
#include <hip/hip_runtime.h>
#include <math.h>

#define N_NODES 50000
#define N_EDGES 800000
#define E_TOT   (N_EDGES + N_NODES)   // 850000, self-loops appended
#define IN_DIM  32
#define HID     96
#define NEG_SLOPE 0.2f
#define MAXD    256                   // LDS chunk per wave (max in-degree fast chunk)
#define SCAN_BS 1024
#define N_SCAN_BLOCKS ((N_NODES + SCAN_BS - 1) / SCAN_BS)   // 49

static inline int cdiv(long long a, int b) { return (int)((a + b - 1) / b); }

// ---------------- CSR build (counting sort by dst), once per launch ----------------

__global__ void hist_kernel(const int* __restrict__ ei, unsigned* __restrict__ deg) {
    int e = blockIdx.x * blockDim.x + threadIdx.x;
    if (e >= E_TOT) return;
    int d = (e < N_EDGES) ? ei[N_EDGES + e] : (e - N_EDGES);
    atomicAdd(deg + d, 1u);
}

// per-block exclusive scan; writes exclusive values into rs, block totals into bsums
__global__ void scan_block_kernel(const unsigned* __restrict__ deg, unsigned* __restrict__ rs,
                                  unsigned* __restrict__ bsums, int n) {
    __shared__ unsigned buf[SCAN_BS];
    int i = blockIdx.x * SCAN_BS + threadIdx.x;
    unsigned v = (i < n) ? deg[i] : 0u;
    buf[threadIdx.x] = v;
    __syncthreads();
    for (int o = 1; o < SCAN_BS; o <<= 1) {
        unsigned t = (threadIdx.x >= (unsigned)o) ? buf[threadIdx.x - o] : 0u;
        __syncthreads();
        buf[threadIdx.x] += t;
        __syncthreads();
    }
    if (i < n) rs[i] = buf[threadIdx.x] - v;          // exclusive within block
    if (threadIdx.x == SCAN_BS - 1) bsums[blockIdx.x] = buf[SCAN_BS - 1];
}

// single-wave exclusive scan of the (<=64) block sums
__global__ void scan_sums_kernel(const unsigned* __restrict__ bsums, unsigned* __restrict__ boffs, int nb) {
    int lane = threadIdx.x;
    unsigned v = (lane < nb) ? bsums[lane] : 0u;
    unsigned incl = v;
    #pragma unroll
    for (int o = 1; o < 64; o <<= 1) {
        unsigned t = __shfl_up(incl, o);
        if (lane >= o) incl += t;
    }
    if (lane < nb) boffs[lane] = incl - v;
}

// add block offsets; produce final row starts (rs) and write cursors (wptr); rs[n] = E_TOT
__global__ void scan_fix_kernel(unsigned* __restrict__ rs, const unsigned* __restrict__ boffs,
                                unsigned* __restrict__ wptr, int n) {
    int i = blockIdx.x * blockDim.x + threadIdx.x;
    if (i < n) {
        unsigned r = rs[i] + boffs[i >> 10];
        rs[i] = r;
        wptr[i] = r;
    }
    if (i == n) rs[n] = E_TOT;
}

__global__ void fill_kernel(const int* __restrict__ ei, unsigned* __restrict__ wptr,
                            int* __restrict__ srcs) {
    int e = blockIdx.x * blockDim.x + threadIdx.x;
    if (e >= E_TOT) return;
    int s, d;
    if (e < N_EDGES) { s = ei[e]; d = ei[N_EDGES + e]; }
    else             { s = d = e - N_EDGES; }
    unsigned pos = atomicAdd(wptr + d, 1u);
    srcs[pos] = s;
}

// ---------------- per-layer dense kernels ----------------

// h = x @ W for dout=96; thread computes 4 consecutive channels (float4 on W rows)
__global__ void gemm4_kernel(const float* __restrict__ x, const float* __restrict__ W,
                             float* __restrict__ h, int n, int din) {
    int idx = blockIdx.x * blockDim.x + threadIdx.x;   // n * 24 threads
    if (idx >= n * 24) return;
    int node = idx / 24;
    int c4 = (idx - node * 24) * 4;
    const float* xr = x + (long long)node * din;
    float a0 = 0.f, a1 = 0.f, a2 = 0.f, a3 = 0.f;
    #pragma unroll 8
    for (int k = 0; k < din; ++k) {
        float xv = xr[k];
        const float4 w = *(const float4*)(W + k * 96 + c4);
        a0 += xv * w.x; a1 += xv * w.y; a2 += xv * w.z; a3 += xv * w.w;
    }
    float4 r; r.x = a0; r.y = a1; r.z = a2; r.w = a3;
    *(float4*)(h + (long long)node * 96 + c4) = r;
}

// es[i] = h[i,:]·a_s ; ed[i] = h[i,:]·a_d   (one wave per node, dout=96)
__global__ void scores_kernel(const float* __restrict__ h, const float* __restrict__ a_s,
                              const float* __restrict__ a_d, float* __restrict__ es,
                              float* __restrict__ ed, int n) {
    int node = (int)((blockIdx.x * (long long)blockDim.x + threadIdx.x) >> 6);
    int lane = threadIdx.x & 63;
    if (node >= n) return;
    float ps = 0.f, pd = 0.f;
    for (int c = lane; c < HID; c += 64) {
        float hv = h[(long long)node * HID + c];
        ps += hv * a_s[c];
        pd += hv * a_d[c];
    }
    #pragma unroll
    for (int o = 32; o; o >>= 1) {
        ps += __shfl_xor(ps, o);
        pd += __shfl_xor(pd, o);
    }
    if (lane == 0) { es[node] = ps; ed[node] = pd; }
}

// final layer projection fused: h=x@Wf (96->1), es=h*asf, ed=h*adf (wave per node)
__global__ void final_proj_kernel(const float* __restrict__ x, const float* __restrict__ Wf,
                                  const float* __restrict__ asf, const float* __restrict__ adf,
                                  float* __restrict__ h, float* __restrict__ es,
                                  float* __restrict__ ed, int n) {
    int node = (int)((blockIdx.x * (long long)blockDim.x + threadIdx.x) >> 6);
    int lane = threadIdx.x & 63;
    if (node >= n) return;
    const float* xr = x + (long long)node * HID;
    float p = 0.f;
    for (int c = lane; c < HID; c += 64) p += xr[c] * Wf[c];
    #pragma unroll
    for (int o = 32; o; o >>= 1) p += __shfl_xor(p, o);
    if (lane == 0) {
        h[node] = p;
        es[node] = p * asf[0];
        ed[node] = p * adf[0];
    }
}

// ---------------- fused segment-softmax + gather-accumulate ----------------
// One wave per destination node. No atomics, no barriers (per-wave LDS slices).
// acc = sum_j exp(e_j - m) * h[src_j]; out = acc / sum + b (+res) (relu)
template<int DOUT>
__global__ __launch_bounds__(256) void aggregate_kernel(
    const unsigned* __restrict__ rs, const int* __restrict__ srcs,
    const float* __restrict__ es, const float* __restrict__ ed,
    const float* __restrict__ h, const float* __restrict__ b,
    const float* __restrict__ res, float* __restrict__ out, int do_relu) {
    __shared__ float sh_ex[4][MAXD];
    __shared__ int   sh_sr[4][MAXD];
    int node = (int)((blockIdx.x * (long long)blockDim.x + threadIdx.x) >> 6);
    int lane = threadIdx.x & 63;
    int wv = threadIdx.x >> 6;
    if (node >= N_NODES) return;
    unsigned row = rs[node];
    int deg = (int)(rs[node + 1] - row);
    float edv = ed[node];

    // pass 1: segment max (recompute logits; es is tiny and L2-hot)
    float lmax = -1e30f;
    for (int j = lane; j < deg; j += 64) {
        int s = srcs[row + j];
        float v = es[s] + edv;
        v = v > 0.f ? v : NEG_SLOPE * v;
        lmax = fmaxf(lmax, v);
    }
    #pragma unroll
    for (int o = 32; o; o >>= 1) lmax = fmaxf(lmax, __shfl_xor(lmax, o));

    // pass 2: chunks — exp into this wave's LDS slice, then gather-accumulate
    float lsum = 0.f;
    float acc0 = 0.f, acc1 = 0.f;
    for (int base = 0; base < deg; base += MAXD) {
        int cnt = min(MAXD, deg - base);
        for (int j = lane; j < cnt; j += 64) {
            int s = srcs[row + base + j];
            float v = es[s] + edv;
            v = v > 0.f ? v : NEG_SLOPE * v;
            float ex = __expf(v - lmax);
            sh_ex[wv][j] = ex;
            sh_sr[wv][j] = s;
            lsum += ex;
        }
        // same-wave LDS RAW: compiler orders via lgkmcnt; LDS has no per-lane caching
        if (DOUT == HID) {
            for (int j = 0; j < cnt; ++j) {
                float exv = sh_ex[wv][j];                  // broadcast read
                const float* hr = h + (long long)sh_sr[wv][j] * HID;
                acc0 += exv * hr[lane];
                if (lane < 32) acc1 += exv * hr[64 + lane];
            }
        } else {
            for (int j = lane; j < cnt; j += 64)
                acc0 += sh_ex[wv][j] * h[sh_sr[wv][j]];
        }
    }
    #pragma unroll
    for (int o = 32; o; o >>= 1) lsum += __shfl_xor(lsum, o);
    float inv = 1.f / lsum;

    if (DOUT == HID) {
        float v0 = acc0 * inv + b[lane];
        if (res) v0 += res[(long long)node * HID + lane];
        if (do_relu) v0 = fmaxf(v0, 0.f);
        out[(long long)node * HID + lane] = v0;
        if (lane < 32) {
            float v1 = acc1 * inv + b[64 + lane];
            if (res) v1 += res[(long long)node * HID + 64 + lane];
            if (do_relu) v1 = fmaxf(v1, 0.f);
            out[(long long)node * HID + 64 + lane] = v1;
        }
    } else {
        #pragma unroll
        for (int o = 32; o; o >>= 1) acc0 += __shfl_xor(acc0, o);
        if (lane == 0) out[node] = acc0 * inv + b[0];
    }
}

// ---------------- host-side orchestration ----------------

extern "C" void kernel_launch(void* const* d_in, const int* in_sizes, int n_in,
                              void* d_out, int out_size, void* d_ws, size_t ws_size,
                              hipStream_t stream) {
    const float* x  = (const float*)d_in[0];
    const int*   ei = (const int*)d_in[1];   // [2, N_EDGES] row-major int32
    const float* W0 = (const float*)d_in[3];
    const float* as0 = (const float*)d_in[4];
    const float* ad0 = (const float*)d_in[5];
    const float* b0 = (const float*)d_in[6];
    const float* W1 = (const float*)d_in[7];
    const float* as1 = (const float*)d_in[8];
    const float* ad1 = (const float*)d_in[9];
    const float* b1 = (const float*)d_in[10];
    const float* W2 = (const float*)d_in[11];
    const float* as2 = (const float*)d_in[12];
    const float* ad2 = (const float*)d_in[13];
    const float* b2 = (const float*)d_in[14];
    const float* Wf = (const float*)d_in[15];
    const float* asf = (const float*)d_in[16];
    const float* adf = (const float*)d_in[17];
    const float* bf = (const float*)d_in[18];

    float* out = (float*)d_out;  // 50000 floats

    // workspace carve-up (floats) — total ~15.45M floats ≈ 61.8 MB
    float* H  = (float*)d_ws;                    // N*96
    float* FA = H  + (long long)N_NODES * HID;   // N*96
    float* FB = FA + (long long)N_NODES * HID;   // N*96
    float* ES = FB + (long long)N_NODES * HID;   // N
    float* ED = ES + N_NODES;                    // N
    unsigned* RS   = (unsigned*)(ED + N_NODES);  // N+1
    unsigned* WPTR = RS + (N_NODES + 1);         // N
    int* SRCS = (int*)(WPTR + N_NODES);          // E_TOT
    // CSR-build-only temporaries aliased onto H (H written only after CSR done)
    unsigned* DEG = (unsigned*)H;                // N
    unsigned* BS  = DEG + N_NODES;               // 64
    unsigned* BO  = BS + 64;                     // 64

    // ---- CSR build (amortized over all 4 layers) ----
    hipMemsetAsync(DEG, 0, (size_t)N_NODES * sizeof(unsigned), stream);
    hist_kernel<<<cdiv(E_TOT, 256), 256, 0, stream>>>(ei, DEG);
    scan_block_kernel<<<N_SCAN_BLOCKS, SCAN_BS, 0, stream>>>(DEG, RS, BS, N_NODES);
    scan_sums_kernel<<<1, 64, 0, stream>>>(BS, BO, N_SCAN_BLOCKS);
    scan_fix_kernel<<<cdiv(N_NODES + 1, 256), 256, 0, stream>>>(RS, BO, WPTR, N_NODES);
    fill_kernel<<<cdiv(E_TOT, 256), 256, 0, stream>>>(ei, WPTR, SRCS);

    // ---- layer 0: x(32) -> FA(96), relu, no residual ----
    gemm4_kernel<<<cdiv((long long)N_NODES * 24, 256), 256, 0, stream>>>(x, W0, H, N_NODES, IN_DIM);
    scores_kernel<<<cdiv(N_NODES, 4), 256, 0, stream>>>(H, as0, ad0, ES, ED, N_NODES);
    aggregate_kernel<HID><<<cdiv(N_NODES, 4), 256, 0, stream>>>(RS, SRCS, ES, ED, H, b0, nullptr, FA, 1);

    // ---- layer 1: FA -> FB, residual FA, relu ----
    gemm4_kernel<<<cdiv((long long)N_NODES * 24, 256), 256, 0, stream>>>(FA, W1, H, N_NODES, HID);
    scores_kernel<<<cdiv(N_NODES, 4), 256, 0, stream>>>(H, as1, ad1, ES, ED, N_NODES);
    aggregate_kernel<HID><<<cdiv(N_NODES, 4), 256, 0, stream>>>(RS, SRCS, ES, ED, H, b1, FA, FB, 1);

    // ---- layer 2: FB -> FA, residual FB, relu ----
    gemm4_kernel<<<cdiv((long long)N_NODES * 24, 256), 256, 0, stream>>>(FB, W2, H, N_NODES, HID);
    scores_kernel<<<cdiv(N_NODES, 4), 256, 0, stream>>>(H, as2, ad2, ES, ED, N_NODES);
    aggregate_kernel<HID><<<cdiv(N_NODES, 4), 256, 0, stream>>>(RS, SRCS, ES, ED, H, b2, FB, FA, 1);

    // ---- final: FA -> out (dout=1) ----
    final_proj_kernel<<<cdiv(N_NODES, 4), 256, 0, stream>>>(FA, Wf, asf, adf, H, ES, ED, N_NODES);
    aggregate_kernel<1><<<cdiv(N_NODES, 4), 256, 0, stream>>>(RS, SRCS, ES, ED, H, bf, nullptr, out, 0);
}

// Round 3
// 545.815 us; speedup vs baseline: 3.0718x; 1.1505x over previous
//
#include <hip/hip_runtime.h>
#include <math.h>

#define N_NODES 50000
#define N_EDGES 800000
#define E_TOT   (N_EDGES + N_NODES)   // 850000, self-loops appended
#define IN_DIM  32
#define HID     96
#define NEG_SLOPE 0.2f
#define MAXD    256                   // LDS chunk per wave
#define SCAN_BS 1024
#define N_SCAN_BLOCKS ((N_NODES + SCAN_BS - 1) / SCAN_BS)   // 49

static inline int cdiv(long long a, int b) { return (int)((a + b - 1) / b); }

// ---------------- CSR build (counting sort by dst), once per launch ----------------

__global__ void hist_kernel(const int* __restrict__ ei, unsigned* __restrict__ deg) {
    int e = blockIdx.x * blockDim.x + threadIdx.x;
    if (e >= E_TOT) return;
    int d = (e < N_EDGES) ? ei[N_EDGES + e] : (e - N_EDGES);
    atomicAdd(deg + d, 1u);
}

__global__ void scan_block_kernel(const unsigned* __restrict__ deg, unsigned* __restrict__ rs,
                                  unsigned* __restrict__ bsums, int n) {
    __shared__ unsigned buf[SCAN_BS];
    int i = blockIdx.x * SCAN_BS + threadIdx.x;
    unsigned v = (i < n) ? deg[i] : 0u;
    buf[threadIdx.x] = v;
    __syncthreads();
    for (int o = 1; o < SCAN_BS; o <<= 1) {
        unsigned t = (threadIdx.x >= (unsigned)o) ? buf[threadIdx.x - o] : 0u;
        __syncthreads();
        buf[threadIdx.x] += t;
        __syncthreads();
    }
    if (i < n) rs[i] = buf[threadIdx.x] - v;
    if (threadIdx.x == SCAN_BS - 1) bsums[blockIdx.x] = buf[SCAN_BS - 1];
}

__global__ void scan_sums_kernel(const unsigned* __restrict__ bsums, unsigned* __restrict__ boffs, int nb) {
    int lane = threadIdx.x;
    unsigned v = (lane < nb) ? bsums[lane] : 0u;
    unsigned incl = v;
    #pragma unroll
    for (int o = 1; o < 64; o <<= 1) {
        unsigned t = __shfl_up(incl, o);
        if (lane >= o) incl += t;
    }
    if (lane < nb) boffs[lane] = incl - v;
}

__global__ void scan_fix_kernel(unsigned* __restrict__ rs, const unsigned* __restrict__ boffs,
                                unsigned* __restrict__ wptr, int n) {
    int i = blockIdx.x * blockDim.x + threadIdx.x;
    if (i < n) {
        unsigned r = rs[i] + boffs[i >> 10];
        rs[i] = r;
        wptr[i] = r;
    }
    if (i == n) rs[n] = E_TOT;
}

__global__ void fill_kernel(const int* __restrict__ ei, unsigned* __restrict__ wptr,
                            int* __restrict__ srcs) {
    int e = blockIdx.x * blockDim.x + threadIdx.x;
    if (e >= E_TOT) return;
    int s, d;
    if (e < N_EDGES) { s = ei[e]; d = ei[N_EDGES + e]; }
    else             { s = d = e - N_EDGES; }
    unsigned pos = atomicAdd(wptr + d, 1u);
    srcs[pos] = s;
}

// ---------------- per-layer dense kernels ----------------

__global__ void gemm4_kernel(const float* __restrict__ x, const float* __restrict__ W,
                             float* __restrict__ h, int n, int din) {
    int idx = blockIdx.x * blockDim.x + threadIdx.x;   // n * 24 threads
    if (idx >= n * 24) return;
    int node = idx / 24;
    int c4 = (idx - node * 24) * 4;
    const float* xr = x + (long long)node * din;
    float a0 = 0.f, a1 = 0.f, a2 = 0.f, a3 = 0.f;
    #pragma unroll 8
    for (int k = 0; k < din; ++k) {
        float xv = xr[k];
        const float4 w = *(const float4*)(W + k * 96 + c4);
        a0 += xv * w.x; a1 += xv * w.y; a2 += xv * w.z; a3 += xv * w.w;
    }
    float4 r; r.x = a0; r.y = a1; r.z = a2; r.w = a3;
    *(float4*)(h + (long long)node * 96 + c4) = r;
}

__global__ void scores_kernel(const float* __restrict__ h, const float* __restrict__ a_s,
                              const float* __restrict__ a_d, float* __restrict__ es,
                              float* __restrict__ ed, int n) {
    int node = (int)((blockIdx.x * (long long)blockDim.x + threadIdx.x) >> 6);
    int lane = threadIdx.x & 63;
    if (node >= n) return;
    float ps = 0.f, pd = 0.f;
    for (int c = lane; c < HID; c += 64) {
        float hv = h[(long long)node * HID + c];
        ps += hv * a_s[c];
        pd += hv * a_d[c];
    }
    #pragma unroll
    for (int o = 32; o; o >>= 1) {
        ps += __shfl_xor(ps, o);
        pd += __shfl_xor(pd, o);
    }
    if (lane == 0) { es[node] = ps; ed[node] = pd; }
}

__global__ void final_proj_kernel(const float* __restrict__ x, const float* __restrict__ Wf,
                                  const float* __restrict__ asf, const float* __restrict__ adf,
                                  float* __restrict__ h, float* __restrict__ es,
                                  float* __restrict__ ed, int n) {
    int node = (int)((blockIdx.x * (long long)blockDim.x + threadIdx.x) >> 6);
    int lane = threadIdx.x & 63;
    if (node >= n) return;
    const float* xr = x + (long long)node * HID;
    float p = 0.f;
    for (int c = lane; c < HID; c += 64) p += xr[c] * Wf[c];
    #pragma unroll
    for (int o = 32; o; o >>= 1) p += __shfl_xor(p, o);
    if (lane == 0) {
        h[node] = p;
        es[node] = p * asf[0];
        ed[node] = p * adf[0];
    }
}

// ---------------- fused segment-softmax + gather-accumulate (dout=96) ----------------
// One wave per destination node. float2 per lane (48 active lanes = 96 channels),
// gather unrolled x4 for memory-level parallelism. No atomics, no barriers.
__global__ __launch_bounds__(256) void aggregate96_kernel(
    const unsigned* __restrict__ rs, const int* __restrict__ srcs,
    const float* __restrict__ es, const float* __restrict__ ed,
    const float* __restrict__ h, const float* __restrict__ b,
    const float* __restrict__ res, float* __restrict__ out, int do_relu) {
    __shared__ float sh_v[4][MAXD];
    __shared__ int   sh_sr[4][MAXD];
    int node = (int)((blockIdx.x * (long long)blockDim.x + threadIdx.x) >> 6);
    int lane = threadIdx.x & 63;
    int wv = threadIdx.x >> 6;
    if (node >= N_NODES) return;
    unsigned row = rs[node];
    int deg = (int)(rs[node + 1] - row);
    float edv = ed[node];
    bool single = (deg <= MAXD);   // wave-uniform

    // pass 1: segment max; stage (src, logit) in LDS for the common single-chunk case
    float lmax = -1e30f;
    for (int j = lane; j < deg; j += 64) {
        int s = srcs[row + j];
        float v = es[s] + edv;
        v = v > 0.f ? v : NEG_SLOPE * v;
        if (single) { sh_sr[wv][j] = s; sh_v[wv][j] = v; }
        lmax = fmaxf(lmax, v);
    }
    #pragma unroll
    for (int o = 32; o; o >>= 1) lmax = fmaxf(lmax, __shfl_xor(lmax, o));

    float lsum = 0.f;
    float accx = 0.f, accy = 0.f;
    const float2* h2 = (const float2*)h;

    for (int base = 0; base < deg; base += MAXD) {
        int cnt = min(MAXD, deg - base);
        // exp into LDS (same-wave RAW, ordered by lgkmcnt)
        for (int j = lane; j < cnt; j += 64) {
            int s; float v;
            if (single) { s = sh_sr[wv][j]; v = sh_v[wv][j]; }
            else {
                s = srcs[row + base + j];
                v = es[s] + edv;
                v = v > 0.f ? v : NEG_SLOPE * v;
                sh_sr[wv][j] = s;
            }
            float ex = __expf(v - lmax);
            sh_v[wv][j] = ex;
            lsum += ex;
        }
        // gather-accumulate, 4 rows in flight
        int j = 0;
        for (; j + 4 <= cnt; j += 4) {
            int   s0 = sh_sr[wv][j],     s1 = sh_sr[wv][j + 1];
            int   s2 = sh_sr[wv][j + 2], s3 = sh_sr[wv][j + 3];
            float e0 = sh_v[wv][j],      e1 = sh_v[wv][j + 1];
            float e2 = sh_v[wv][j + 2],  e3 = sh_v[wv][j + 3];
            if (lane < 48) {
                float2 v0 = h2[(size_t)s0 * 48 + lane];
                float2 v1 = h2[(size_t)s1 * 48 + lane];
                float2 v2 = h2[(size_t)s2 * 48 + lane];
                float2 v3 = h2[(size_t)s3 * 48 + lane];
                accx += e0 * v0.x + e1 * v1.x + e2 * v2.x + e3 * v3.x;
                accy += e0 * v0.y + e1 * v1.y + e2 * v2.y + e3 * v3.y;
            }
        }
        for (; j < cnt; ++j) {
            int s = sh_sr[wv][j];
            float e = sh_v[wv][j];
            if (lane < 48) {
                float2 v = h2[(size_t)s * 48 + lane];
                accx += e * v.x;
                accy += e * v.y;
            }
        }
    }
    #pragma unroll
    for (int o = 32; o; o >>= 1) lsum += __shfl_xor(lsum, o);

    if (lane < 48) {
        float inv = 1.f / lsum;
        float2 bb = ((const float2*)b)[lane];
        float vx = accx * inv + bb.x;
        float vy = accy * inv + bb.y;
        if (res) {
            float2 rr = ((const float2*)(res + (size_t)node * HID))[lane];
            vx += rr.x; vy += rr.y;
        }
        if (do_relu) { vx = fmaxf(vx, 0.f); vy = fmaxf(vy, 0.f); }
        float2 o2; o2.x = vx; o2.y = vy;
        ((float2*)(out + (size_t)node * HID))[lane] = o2;
    }
}

// ---------------- dout=1 aggregate (final layer): no LDS needed ----------------
__global__ __launch_bounds__(256) void aggregate1_kernel(
    const unsigned* __restrict__ rs, const int* __restrict__ srcs,
    const float* __restrict__ es, const float* __restrict__ ed,
    const float* __restrict__ h, const float* __restrict__ b,
    float* __restrict__ out) {
    int node = (int)((blockIdx.x * (long long)blockDim.x + threadIdx.x) >> 6);
    int lane = threadIdx.x & 63;
    if (node >= N_NODES) return;
    unsigned row = rs[node];
    int deg = (int)(rs[node + 1] - row);
    float edv = ed[node];

    float lmax = -1e30f;
    for (int j = lane; j < deg; j += 64) {
        int s = srcs[row + j];
        float v = es[s] + edv;
        v = v > 0.f ? v : NEG_SLOPE * v;
        lmax = fmaxf(lmax, v);
    }
    #pragma unroll
    for (int o = 32; o; o >>= 1) lmax = fmaxf(lmax, __shfl_xor(lmax, o));

    float lsum = 0.f, acc = 0.f;
    for (int j = lane; j < deg; j += 64) {
        int s = srcs[row + j];
        float v = es[s] + edv;
        v = v > 0.f ? v : NEG_SLOPE * v;
        float ex = __expf(v - lmax);
        lsum += ex;
        acc += ex * h[s];
    }
    #pragma unroll
    for (int o = 32; o; o >>= 1) {
        lsum += __shfl_xor(lsum, o);
        acc  += __shfl_xor(acc, o);
    }
    if (lane == 0) out[node] = acc / lsum + b[0];
}

// ---------------- host-side orchestration ----------------

extern "C" void kernel_launch(void* const* d_in, const int* in_sizes, int n_in,
                              void* d_out, int out_size, void* d_ws, size_t ws_size,
                              hipStream_t stream) {
    const float* x  = (const float*)d_in[0];
    const int*   ei = (const int*)d_in[1];
    const float* W0 = (const float*)d_in[3];
    const float* as0 = (const float*)d_in[4];
    const float* ad0 = (const float*)d_in[5];
    const float* b0 = (const float*)d_in[6];
    const float* W1 = (const float*)d_in[7];
    const float* as1 = (const float*)d_in[8];
    const float* ad1 = (const float*)d_in[9];
    const float* b1 = (const float*)d_in[10];
    const float* W2 = (const float*)d_in[11];
    const float* as2 = (const float*)d_in[12];
    const float* ad2 = (const float*)d_in[13];
    const float* b2 = (const float*)d_in[14];
    const float* Wf = (const float*)d_in[15];
    const float* asf = (const float*)d_in[16];
    const float* adf = (const float*)d_in[17];
    const float* bf = (const float*)d_in[18];

    float* out = (float*)d_out;  // 50000 floats

    // workspace carve-up (floats)
    float* H  = (float*)d_ws;                    // N*96
    float* FA = H  + (long long)N_NODES * HID;   // N*96
    float* FB = FA + (long long)N_NODES * HID;   // N*96
    float* ES = FB + (long long)N_NODES * HID;   // N
    float* ED = ES + N_NODES;                    // N
    unsigned* RS   = (unsigned*)(ED + N_NODES);  // N+1
    unsigned* WPTR = RS + (N_NODES + 1);         // N
    int* SRCS = (int*)(WPTR + N_NODES);          // E_TOT
    unsigned* DEG = (unsigned*)H;                // CSR temporaries aliased onto H
    unsigned* BS  = DEG + N_NODES;
    unsigned* BO  = BS + 64;

    // ---- CSR build ----
    hipMemsetAsync(DEG, 0, (size_t)N_NODES * sizeof(unsigned), stream);
    hist_kernel<<<cdiv(E_TOT, 256), 256, 0, stream>>>(ei, DEG);
    scan_block_kernel<<<N_SCAN_BLOCKS, SCAN_BS, 0, stream>>>(DEG, RS, BS, N_NODES);
    scan_sums_kernel<<<1, 64, 0, stream>>>(BS, BO, N_SCAN_BLOCKS);
    scan_fix_kernel<<<cdiv(N_NODES + 1, 256), 256, 0, stream>>>(RS, BO, WPTR, N_NODES);
    fill_kernel<<<cdiv(E_TOT, 256), 256, 0, stream>>>(ei, WPTR, SRCS);

    // ---- layer 0: x(32) -> FA(96), relu, no residual ----
    gemm4_kernel<<<cdiv((long long)N_NODES * 24, 256), 256, 0, stream>>>(x, W0, H, N_NODES, IN_DIM);
    scores_kernel<<<cdiv(N_NODES, 4), 256, 0, stream>>>(H, as0, ad0, ES, ED, N_NODES);
    aggregate96_kernel<<<cdiv(N_NODES, 4), 256, 0, stream>>>(RS, SRCS, ES, ED, H, b0, nullptr, FA, 1);

    // ---- layer 1: FA -> FB, residual FA, relu ----
    gemm4_kernel<<<cdiv((long long)N_NODES * 24, 256), 256, 0, stream>>>(FA, W1, H, N_NODES, HID);
    scores_kernel<<<cdiv(N_NODES, 4), 256, 0, stream>>>(H, as1, ad1, ES, ED, N_NODES);
    aggregate96_kernel<<<cdiv(N_NODES, 4), 256, 0, stream>>>(RS, SRCS, ES, ED, H, b1, FA, FB, 1);

    // ---- layer 2: FB -> FA, residual FB, relu ----
    gemm4_kernel<<<cdiv((long long)N_NODES * 24, 256), 256, 0, stream>>>(FB, W2, H, N_NODES, HID);
    scores_kernel<<<cdiv(N_NODES, 4), 256, 0, stream>>>(H, as2, ad2, ES, ED, N_NODES);
    aggregate96_kernel<<<cdiv(N_NODES, 4), 256, 0, stream>>>(RS, SRCS, ES, ED, H, b2, FB, FA, 1);

    // ---- final: FA -> out (dout=1) ----
    final_proj_kernel<<<cdiv(N_NODES, 4), 256, 0, stream>>>(FA, Wf, asf, adf, H, ES, ED, N_NODES);
    aggregate1_kernel<<<cdiv(N_NODES, 4), 256, 0, stream>>>(RS, SRCS, ES, ED, H, bf, out);
}

// Round 4
// 435.927 us; speedup vs baseline: 3.8462x; 1.2521x over previous
//
#include <hip/hip_runtime.h>
#include <hip/hip_fp16.h>
#include <math.h>

#define N_NODES 50000
#define N_EDGES 800000
#define E_TOT   (N_EDGES + N_NODES)   // 850000, self-loops appended
#define IN_DIM  32
#define HID     96
#define NEG_SLOPE 0.2f
#define MAXD    256                   // LDS chunk per wave
#define SCAN_BS 1024
#define N_SCAN_BLOCKS ((N_NODES + SCAN_BS - 1) / SCAN_BS)   // 49

static inline int cdiv(long long a, int b) { return (int)((a + b - 1) / b); }

// ---------------- CSR build (counting sort by dst), once per launch ----------------

__global__ void hist_kernel(const int* __restrict__ ei, unsigned* __restrict__ deg) {
    int e = blockIdx.x * blockDim.x + threadIdx.x;
    if (e >= E_TOT) return;
    int d = (e < N_EDGES) ? ei[N_EDGES + e] : (e - N_EDGES);
    atomicAdd(deg + d, 1u);
}

__global__ void scan_block_kernel(const unsigned* __restrict__ deg, unsigned* __restrict__ rs,
                                  unsigned* __restrict__ bsums, int n) {
    __shared__ unsigned buf[SCAN_BS];
    int i = blockIdx.x * SCAN_BS + threadIdx.x;
    unsigned v = (i < n) ? deg[i] : 0u;
    buf[threadIdx.x] = v;
    __syncthreads();
    for (int o = 1; o < SCAN_BS; o <<= 1) {
        unsigned t = (threadIdx.x >= (unsigned)o) ? buf[threadIdx.x - o] : 0u;
        __syncthreads();
        buf[threadIdx.x] += t;
        __syncthreads();
    }
    if (i < n) rs[i] = buf[threadIdx.x] - v;
    if (threadIdx.x == SCAN_BS - 1) bsums[blockIdx.x] = buf[SCAN_BS - 1];
}

__global__ void scan_sums_kernel(const unsigned* __restrict__ bsums, unsigned* __restrict__ boffs, int nb) {
    int lane = threadIdx.x;
    unsigned v = (lane < nb) ? bsums[lane] : 0u;
    unsigned incl = v;
    #pragma unroll
    for (int o = 1; o < 64; o <<= 1) {
        unsigned t = __shfl_up(incl, o);
        if (lane >= o) incl += t;
    }
    if (lane < nb) boffs[lane] = incl - v;
}

__global__ void scan_fix_kernel(unsigned* __restrict__ rs, const unsigned* __restrict__ boffs,
                                unsigned* __restrict__ wptr, int n) {
    int i = blockIdx.x * blockDim.x + threadIdx.x;
    if (i < n) {
        unsigned r = rs[i] + boffs[i >> 10];
        rs[i] = r;
        wptr[i] = r;
    }
    if (i == n) rs[n] = E_TOT;
}

__global__ void fill_kernel(const int* __restrict__ ei, unsigned* __restrict__ wptr,
                            int* __restrict__ srcs) {
    int e = blockIdx.x * blockDim.x + threadIdx.x;
    if (e >= E_TOT) return;
    int s, d;
    if (e < N_EDGES) { s = ei[e]; d = ei[N_EDGES + e]; }
    else             { s = d = e - N_EDGES; }
    unsigned pos = atomicAdd(wptr + d, 1u);
    srcs[pos] = s;
}

// ---------------- GEMM: 4-node x 4-channel micro-tile per thread, fp16 output ----------------

__device__ __forceinline__ void fma4(float4& a, float s, const float4& w) {
    a.x += s * w.x; a.y += s * w.y; a.z += s * w.z; a.w += s * w.w;
}

// n must be divisible by 4; dout=96. h output is fp16 (96 halves per row).
__global__ void gemm_h16_kernel(const float* __restrict__ x, const float* __restrict__ W,
                                __half* __restrict__ h, int n, int din) {
    int idx = blockIdx.x * blockDim.x + threadIdx.x;   // (n/4)*24 threads
    int ngroups = n >> 2;
    if (idx >= ngroups * 24) return;
    int g   = idx / 24;
    int c4q = idx - g * 24;          // float4 column index (channel = c4q*4)
    int n0 = g * 4;
    int k4n = din >> 2;
    const float4* X4 = (const float4*)x;
    const float4* W4 = (const float4*)W;   // row stride 24 float4
    const float4* Xa = X4 + (size_t)n0 * k4n;
    const float4* Xb = Xa + k4n;
    const float4* Xc = Xb + k4n;
    const float4* Xd = Xc + k4n;

    float4 accA = {0,0,0,0}, accB = {0,0,0,0}, accC = {0,0,0,0}, accD = {0,0,0,0};
    for (int k4 = 0; k4 < k4n; ++k4) {
        float4 xa = Xa[k4], xb = Xb[k4], xc = Xc[k4], xd = Xd[k4];
        #pragma unroll
        for (int kk = 0; kk < 4; ++kk) {
            float4 w = W4[(size_t)(k4 * 4 + kk) * 24 + c4q];
            fma4(accA, ((const float*)&xa)[kk], w);
            fma4(accB, ((const float*)&xb)[kk], w);
            fma4(accC, ((const float*)&xc)[kk], w);
            fma4(accD, ((const float*)&xd)[kk], w);
        }
    }
    // pack 4 fp32 -> 2 half2 -> one 8B store per node
    __half2* H2 = (__half2*)h;
    {
        __half2 p0 = __floats2half2_rn(accA.x, accA.y), p1 = __floats2half2_rn(accA.z, accA.w);
        uint2 st; st.x = *(unsigned*)&p0; st.y = *(unsigned*)&p1;
        *(uint2*)(H2 + (size_t)n0 * 48 + c4q * 2) = st;
    }
    {
        __half2 p0 = __floats2half2_rn(accB.x, accB.y), p1 = __floats2half2_rn(accB.z, accB.w);
        uint2 st; st.x = *(unsigned*)&p0; st.y = *(unsigned*)&p1;
        *(uint2*)(H2 + (size_t)(n0 + 1) * 48 + c4q * 2) = st;
    }
    {
        __half2 p0 = __floats2half2_rn(accC.x, accC.y), p1 = __floats2half2_rn(accC.z, accC.w);
        uint2 st; st.x = *(unsigned*)&p0; st.y = *(unsigned*)&p1;
        *(uint2*)(H2 + (size_t)(n0 + 2) * 48 + c4q * 2) = st;
    }
    {
        __half2 p0 = __floats2half2_rn(accD.x, accD.y), p1 = __floats2half2_rn(accD.z, accD.w);
        uint2 st; st.x = *(unsigned*)&p0; st.y = *(unsigned*)&p1;
        *(uint2*)(H2 + (size_t)(n0 + 3) * 48 + c4q * 2) = st;
    }
}

// es[i] = h[i,:]·a_s ; ed[i] = h[i,:]·a_d   (one wave per node, h fp16)
__global__ void scores_kernel(const __half* __restrict__ h, const float* __restrict__ a_s,
                              const float* __restrict__ a_d, float* __restrict__ es,
                              float* __restrict__ ed, int n) {
    int node = (int)((blockIdx.x * (long long)blockDim.x + threadIdx.x) >> 6);
    int lane = threadIdx.x & 63;
    if (node >= n) return;
    float ps = 0.f, pd = 0.f;
    if (lane < 48) {
        const __half2* h2 = (const __half2*)h + (size_t)node * 48;
        float2 hv = __half22float2(h2[lane]);
        float2 sv = ((const float2*)a_s)[lane];
        float2 dv = ((const float2*)a_d)[lane];
        ps = hv.x * sv.x + hv.y * sv.y;
        pd = hv.x * dv.x + hv.y * dv.y;
    }
    #pragma unroll
    for (int o = 32; o; o >>= 1) {
        ps += __shfl_xor(ps, o);
        pd += __shfl_xor(pd, o);
    }
    if (lane == 0) { es[node] = ps; ed[node] = pd; }
}

// final layer projection fused: h=x@Wf (96->1) from fp32 x, es/ed scalars
__global__ void final_proj_kernel(const float* __restrict__ x, const float* __restrict__ Wf,
                                  const float* __restrict__ asf, const float* __restrict__ adf,
                                  float* __restrict__ h, float* __restrict__ es,
                                  float* __restrict__ ed, int n) {
    int node = (int)((blockIdx.x * (long long)blockDim.x + threadIdx.x) >> 6);
    int lane = threadIdx.x & 63;
    if (node >= n) return;
    const float* xr = x + (long long)node * HID;
    float p = 0.f;
    for (int c = lane; c < HID; c += 64) p += xr[c] * Wf[c];
    #pragma unroll
    for (int o = 32; o; o >>= 1) p += __shfl_xor(p, o);
    if (lane == 0) {
        h[node] = p;
        es[node] = p * asf[0];
        ed[node] = p * adf[0];
    }
}

// ---------------- fused segment-softmax + gather-accumulate (dout=96, fp16 h) ----------------
__global__ __launch_bounds__(256) void aggregate96_kernel(
    const unsigned* __restrict__ rs, const int* __restrict__ srcs,
    const float* __restrict__ es, const float* __restrict__ ed,
    const __half* __restrict__ h, const float* __restrict__ b,
    const float* __restrict__ res, float* __restrict__ out, int do_relu) {
    __shared__ float sh_v[4][MAXD];
    __shared__ int   sh_sr[4][MAXD];
    int node = (int)((blockIdx.x * (long long)blockDim.x + threadIdx.x) >> 6);
    int lane = threadIdx.x & 63;
    int wv = threadIdx.x >> 6;
    if (node >= N_NODES) return;
    unsigned row = rs[node];
    int deg = (int)(rs[node + 1] - row);
    float edv = ed[node];
    bool single = (deg <= MAXD);   // wave-uniform

    // pass 1: segment max; stage (src, logit) in LDS for the single-chunk case
    float lmax = -1e30f;
    for (int j = lane; j < deg; j += 64) {
        int s = srcs[row + j];
        float v = es[s] + edv;
        v = v > 0.f ? v : NEG_SLOPE * v;
        if (single) { sh_sr[wv][j] = s; sh_v[wv][j] = v; }
        lmax = fmaxf(lmax, v);
    }
    #pragma unroll
    for (int o = 32; o; o >>= 1) lmax = fmaxf(lmax, __shfl_xor(lmax, o));

    float lsum = 0.f;
    float accx = 0.f, accy = 0.f;
    const __half2* h2 = (const __half2*)h;

    for (int base = 0; base < deg; base += MAXD) {
        int cnt = min(MAXD, deg - base);
        for (int j = lane; j < cnt; j += 64) {
            int s; float v;
            if (single) { s = sh_sr[wv][j]; v = sh_v[wv][j]; }
            else {
                s = srcs[row + base + j];
                v = es[s] + edv;
                v = v > 0.f ? v : NEG_SLOPE * v;
                sh_sr[wv][j] = s;
            }
            float ex = __expf(v - lmax);
            sh_v[wv][j] = ex;
            lsum += ex;
        }
        // gather-accumulate, 4 rows in flight (fp16 rows: 48 lanes x half2)
        int j = 0;
        for (; j + 4 <= cnt; j += 4) {
            int   s0 = sh_sr[wv][j],     s1 = sh_sr[wv][j + 1];
            int   s2 = sh_sr[wv][j + 2], s3 = sh_sr[wv][j + 3];
            float e0 = sh_v[wv][j],      e1 = sh_v[wv][j + 1];
            float e2 = sh_v[wv][j + 2],  e3 = sh_v[wv][j + 3];
            if (lane < 48) {
                float2 v0 = __half22float2(h2[(size_t)s0 * 48 + lane]);
                float2 v1 = __half22float2(h2[(size_t)s1 * 48 + lane]);
                float2 v2 = __half22float2(h2[(size_t)s2 * 48 + lane]);
                float2 v3 = __half22float2(h2[(size_t)s3 * 48 + lane]);
                accx += e0 * v0.x + e1 * v1.x + e2 * v2.x + e3 * v3.x;
                accy += e0 * v0.y + e1 * v1.y + e2 * v2.y + e3 * v3.y;
            }
        }
        for (; j < cnt; ++j) {
            int s = sh_sr[wv][j];
            float e = sh_v[wv][j];
            if (lane < 48) {
                float2 v = __half22float2(h2[(size_t)s * 48 + lane]);
                accx += e * v.x;
                accy += e * v.y;
            }
        }
    }
    #pragma unroll
    for (int o = 32; o; o >>= 1) lsum += __shfl_xor(lsum, o);

    if (lane < 48) {
        float inv = 1.f / lsum;
        float2 bb = ((const float2*)b)[lane];
        float vx = accx * inv + bb.x;
        float vy = accy * inv + bb.y;
        if (res) {
            float2 rr = ((const float2*)(res + (size_t)node * HID))[lane];
            vx += rr.x; vy += rr.y;
        }
        if (do_relu) { vx = fmaxf(vx, 0.f); vy = fmaxf(vy, 0.f); }
        float2 o2; o2.x = vx; o2.y = vy;
        ((float2*)(out + (size_t)node * HID))[lane] = o2;
    }
}

// ---------------- dout=1 aggregate (final layer, fp32 scalar h) ----------------
__global__ __launch_bounds__(256) void aggregate1_kernel(
    const unsigned* __restrict__ rs, const int* __restrict__ srcs,
    const float* __restrict__ es, const float* __restrict__ ed,
    const float* __restrict__ h, const float* __restrict__ b,
    float* __restrict__ out) {
    int node = (int)((blockIdx.x * (long long)blockDim.x + threadIdx.x) >> 6);
    int lane = threadIdx.x & 63;
    if (node >= N_NODES) return;
    unsigned row = rs[node];
    int deg = (int)(rs[node + 1] - row);
    float edv = ed[node];

    float lmax = -1e30f;
    for (int j = lane; j < deg; j += 64) {
        int s = srcs[row + j];
        float v = es[s] + edv;
        v = v > 0.f ? v : NEG_SLOPE * v;
        lmax = fmaxf(lmax, v);
    }
    #pragma unroll
    for (int o = 32; o; o >>= 1) lmax = fmaxf(lmax, __shfl_xor(lmax, o));

    float lsum = 0.f, acc = 0.f;
    for (int j = lane; j < deg; j += 64) {
        int s = srcs[row + j];
        float v = es[s] + edv;
        v = v > 0.f ? v : NEG_SLOPE * v;
        float ex = __expf(v - lmax);
        lsum += ex;
        acc += ex * h[s];
    }
    #pragma unroll
    for (int o = 32; o; o >>= 1) {
        lsum += __shfl_xor(lsum, o);
        acc  += __shfl_xor(acc, o);
    }
    if (lane == 0) out[node] = acc / lsum + b[0];
}

// ---------------- host-side orchestration ----------------

extern "C" void kernel_launch(void* const* d_in, const int* in_sizes, int n_in,
                              void* d_out, int out_size, void* d_ws, size_t ws_size,
                              hipStream_t stream) {
    const float* x  = (const float*)d_in[0];
    const int*   ei = (const int*)d_in[1];
    const float* W0 = (const float*)d_in[3];
    const float* as0 = (const float*)d_in[4];
    const float* ad0 = (const float*)d_in[5];
    const float* b0 = (const float*)d_in[6];
    const float* W1 = (const float*)d_in[7];
    const float* as1 = (const float*)d_in[8];
    const float* ad1 = (const float*)d_in[9];
    const float* b1 = (const float*)d_in[10];
    const float* W2 = (const float*)d_in[11];
    const float* as2 = (const float*)d_in[12];
    const float* ad2 = (const float*)d_in[13];
    const float* b2 = (const float*)d_in[14];
    const float* Wf = (const float*)d_in[15];
    const float* asf = (const float*)d_in[16];
    const float* adf = (const float*)d_in[17];
    const float* bf = (const float*)d_in[18];

    float* out = (float*)d_out;  // 50000 floats

    // workspace carve-up
    float* Hf = (float*)d_ws;                    // N*96 floats slot (used as fp16 h + final fp32 h)
    __half* H16 = (__half*)Hf;
    float* FA = Hf + (long long)N_NODES * HID;   // N*96
    float* FB = FA + (long long)N_NODES * HID;   // N*96
    float* ES = FB + (long long)N_NODES * HID;   // N
    float* ED = ES + N_NODES;                    // N
    unsigned* RS   = (unsigned*)(ED + N_NODES);  // N+1
    unsigned* WPTR = RS + (N_NODES + 1);         // N
    int* SRCS = (int*)(WPTR + N_NODES);          // E_TOT
    unsigned* DEG = (unsigned*)Hf;               // CSR temporaries aliased onto H slot
    unsigned* BS  = DEG + N_NODES;
    unsigned* BO  = BS + 64;

    // ---- CSR build ----
    hipMemsetAsync(DEG, 0, (size_t)N_NODES * sizeof(unsigned), stream);
    hist_kernel<<<cdiv(E_TOT, 256), 256, 0, stream>>>(ei, DEG);
    scan_block_kernel<<<N_SCAN_BLOCKS, SCAN_BS, 0, stream>>>(DEG, RS, BS, N_NODES);
    scan_sums_kernel<<<1, 64, 0, stream>>>(BS, BO, N_SCAN_BLOCKS);
    scan_fix_kernel<<<cdiv(N_NODES + 1, 256), 256, 0, stream>>>(RS, BO, WPTR, N_NODES);
    fill_kernel<<<cdiv(E_TOT, 256), 256, 0, stream>>>(ei, WPTR, SRCS);

    const int gemm_threads = (N_NODES / 4) * 24;   // 300000

    // ---- layer 0: x(32) -> FA(96), relu, no residual ----
    gemm_h16_kernel<<<cdiv(gemm_threads, 256), 256, 0, stream>>>(x, W0, H16, N_NODES, IN_DIM);
    scores_kernel<<<cdiv(N_NODES, 4), 256, 0, stream>>>(H16, as0, ad0, ES, ED, N_NODES);
    aggregate96_kernel<<<cdiv(N_NODES, 4), 256, 0, stream>>>(RS, SRCS, ES, ED, H16, b0, nullptr, FA, 1);

    // ---- layer 1: FA -> FB, residual FA, relu ----
    gemm_h16_kernel<<<cdiv(gemm_threads, 256), 256, 0, stream>>>(FA, W1, H16, N_NODES, HID);
    scores_kernel<<<cdiv(N_NODES, 4), 256, 0, stream>>>(H16, as1, ad1, ES, ED, N_NODES);
    aggregate96_kernel<<<cdiv(N_NODES, 4), 256, 0, stream>>>(RS, SRCS, ES, ED, H16, b1, FA, FB, 1);

    // ---- layer 2: FB -> FA, residual FB, relu ----
    gemm_h16_kernel<<<cdiv(gemm_threads, 256), 256, 0, stream>>>(FB, W2, H16, N_NODES, HID);
    scores_kernel<<<cdiv(N_NODES, 4), 256, 0, stream>>>(H16, as2, ad2, ES, ED, N_NODES);
    aggregate96_kernel<<<cdiv(N_NODES, 4), 256, 0, stream>>>(RS, SRCS, ES, ED, H16, b2, FB, FA, 1);

    // ---- final: FA -> out (dout=1), fp32 path ----
    final_proj_kernel<<<cdiv(N_NODES, 4), 256, 0, stream>>>(FA, Wf, asf, adf, Hf, ES, ED, N_NODES);
    aggregate1_kernel<<<cdiv(N_NODES, 4), 256, 0, stream>>>(RS, SRCS, ES, ED, Hf, bf, out);
}

// Round 5
// 424.099 us; speedup vs baseline: 3.9534x; 1.0279x over previous
//
#include <hip/hip_runtime.h>
#include <hip/hip_fp16.h>
#include <math.h>

#define N_NODES 50000
#define N_EDGES 800000
#define E_TOT   (N_EDGES + N_NODES)   // 850000, self-loops appended
#define IN_DIM  32
#define HID     96
#define NEG_SLOPE 0.2f
#define MAXD    256                   // LDS chunk per wave
#define SCAN_BS 1024
#define N_SCAN_BLOCKS ((N_NODES + SCAN_BS - 1) / SCAN_BS)   // 49
#define FILL_PASSES 8
#define FILL_WIN (N_NODES / FILL_PASSES)   // 6250

static inline int cdiv(long long a, int b) { return (int)((a + b - 1) / b); }

// ---------------- CSR build (counting sort by dst), once per launch ----------------

__global__ void hist_kernel(const int* __restrict__ ei, unsigned* __restrict__ deg) {
    int e = blockIdx.x * blockDim.x + threadIdx.x;
    if (e >= E_TOT) return;
    int d = (e < N_EDGES) ? ei[N_EDGES + e] : (e - N_EDGES);
    atomicAdd(deg + d, 1u);
}

__global__ void scan_block_kernel(const unsigned* __restrict__ deg, unsigned* __restrict__ rs,
                                  unsigned* __restrict__ bsums, int n) {
    __shared__ unsigned buf[SCAN_BS];
    int i = blockIdx.x * SCAN_BS + threadIdx.x;
    unsigned v = (i < n) ? deg[i] : 0u;
    buf[threadIdx.x] = v;
    __syncthreads();
    for (int o = 1; o < SCAN_BS; o <<= 1) {
        unsigned t = (threadIdx.x >= (unsigned)o) ? buf[threadIdx.x - o] : 0u;
        __syncthreads();
        buf[threadIdx.x] += t;
        __syncthreads();
    }
    if (i < n) rs[i] = buf[threadIdx.x] - v;
    if (threadIdx.x == SCAN_BS - 1) bsums[blockIdx.x] = buf[SCAN_BS - 1];
}

// scan_fix with the (<=49-entry) block-sum prefix computed in-block by wave 0
__global__ void scan_fix_kernel(unsigned* __restrict__ rs, const unsigned* __restrict__ bsums,
                                unsigned* __restrict__ wptr, int n) {
    __shared__ unsigned s_off;
    int k = blockIdx.x >> 2;                  // which 1024-window this block lies in (k <= 48)
    if (threadIdx.x < 64) {
        unsigned v = ((int)threadIdx.x < k) ? bsums[threadIdx.x] : 0u;
        #pragma unroll
        for (int o = 32; o; o >>= 1) v += __shfl_xor(v, o);
        if (threadIdx.x == 0) s_off = v;
    }
    __syncthreads();
    unsigned off = s_off;
    int i = blockIdx.x * 256 + threadIdx.x;
    if (i < n) {
        unsigned r = rs[i] + off;
        rs[i] = r;
        wptr[i] = r;
    }
    if (i == n) rs[n] = E_TOT;
}

// Windowed fill: FILL_PASSES sequential-ish dst-window passes inside one dispatch.
// Pass p only materializes edges with dst in [p*WIN, (p+1)*WIN) -> CSR writes land in
// one contiguous ~425 KB region -> L2 lines fill before eviction (kills write amp).
__global__ void fill_win_kernel(const int* __restrict__ ei, unsigned* __restrict__ wptr,
                                int* __restrict__ srcs) {
    const int nb_e = (E_TOT + 255) / 256;
    int pass = blockIdx.x / nb_e;
    int eb   = blockIdx.x - pass * nb_e;
    int e = eb * 256 + threadIdx.x;
    if (e >= E_TOT) return;
    int lo = pass * FILL_WIN;
    int d = (e < N_EDGES) ? ei[N_EDGES + e] : (e - N_EDGES);
    if ((unsigned)(d - lo) >= (unsigned)FILL_WIN) return;
    int s = (e < N_EDGES) ? ei[e] : d;
    unsigned pos = atomicAdd(wptr + d, 1u);
    srcs[pos] = s;
}

// ---------------- GEMM: 4-node x 4-channel micro-tile per thread, fp16 output ----------------

__device__ __forceinline__ void fma4(float4& a, float s, const float4& w) {
    a.x += s * w.x; a.y += s * w.y; a.z += s * w.z; a.w += s * w.w;
}

__global__ void gemm_h16_kernel(const float* __restrict__ x, const float* __restrict__ W,
                                __half* __restrict__ h, int n, int din) {
    int idx = blockIdx.x * blockDim.x + threadIdx.x;   // (n/4)*24 threads
    int ngroups = n >> 2;
    if (idx >= ngroups * 24) return;
    int g   = idx / 24;
    int c4q = idx - g * 24;          // float4 column index (channel = c4q*4)
    int n0 = g * 4;
    int k4n = din >> 2;
    const float4* X4 = (const float4*)x;
    const float4* W4 = (const float4*)W;   // row stride 24 float4
    const float4* Xa = X4 + (size_t)n0 * k4n;
    const float4* Xb = Xa + k4n;
    const float4* Xc = Xb + k4n;
    const float4* Xd = Xc + k4n;

    float4 accA = {0,0,0,0}, accB = {0,0,0,0}, accC = {0,0,0,0}, accD = {0,0,0,0};
    for (int k4 = 0; k4 < k4n; ++k4) {
        float4 xa = Xa[k4], xb = Xb[k4], xc = Xc[k4], xd = Xd[k4];
        #pragma unroll
        for (int kk = 0; kk < 4; ++kk) {
            float4 w = W4[(size_t)(k4 * 4 + kk) * 24 + c4q];
            fma4(accA, ((const float*)&xa)[kk], w);
            fma4(accB, ((const float*)&xb)[kk], w);
            fma4(accC, ((const float*)&xc)[kk], w);
            fma4(accD, ((const float*)&xd)[kk], w);
        }
    }
    __half2* H2 = (__half2*)h;
    {
        __half2 p0 = __floats2half2_rn(accA.x, accA.y), p1 = __floats2half2_rn(accA.z, accA.w);
        uint2 st; st.x = *(unsigned*)&p0; st.y = *(unsigned*)&p1;
        *(uint2*)(H2 + (size_t)n0 * 48 + c4q * 2) = st;
    }
    {
        __half2 p0 = __floats2half2_rn(accB.x, accB.y), p1 = __floats2half2_rn(accB.z, accB.w);
        uint2 st; st.x = *(unsigned*)&p0; st.y = *(unsigned*)&p1;
        *(uint2*)(H2 + (size_t)(n0 + 1) * 48 + c4q * 2) = st;
    }
    {
        __half2 p0 = __floats2half2_rn(accC.x, accC.y), p1 = __floats2half2_rn(accC.z, accC.w);
        uint2 st; st.x = *(unsigned*)&p0; st.y = *(unsigned*)&p1;
        *(uint2*)(H2 + (size_t)(n0 + 2) * 48 + c4q * 2) = st;
    }
    {
        __half2 p0 = __floats2half2_rn(accD.x, accD.y), p1 = __floats2half2_rn(accD.z, accD.w);
        uint2 st; st.x = *(unsigned*)&p0; st.y = *(unsigned*)&p1;
        *(uint2*)(H2 + (size_t)(n0 + 3) * 48 + c4q * 2) = st;
    }
}

// es[i] = h[i,:]·a_s ; ed[i] = h[i,:]·a_d   (one wave per node, h fp16)
__global__ void scores_kernel(const __half* __restrict__ h, const float* __restrict__ a_s,
                              const float* __restrict__ a_d, float* __restrict__ es,
                              float* __restrict__ ed, int n) {
    int node = (int)((blockIdx.x * (long long)blockDim.x + threadIdx.x) >> 6);
    int lane = threadIdx.x & 63;
    if (node >= n) return;
    float ps = 0.f, pd = 0.f;
    if (lane < 48) {
        const __half2* h2 = (const __half2*)h + (size_t)node * 48;
        float2 hv = __half22float2(h2[lane]);
        float2 sv = ((const float2*)a_s)[lane];
        float2 dv = ((const float2*)a_d)[lane];
        ps = hv.x * sv.x + hv.y * sv.y;
        pd = hv.x * dv.x + hv.y * dv.y;
    }
    #pragma unroll
    for (int o = 32; o; o >>= 1) {
        ps += __shfl_xor(ps, o);
        pd += __shfl_xor(pd, o);
    }
    if (lane == 0) { es[node] = ps; ed[node] = pd; }
}

__global__ void final_proj_kernel(const float* __restrict__ x, const float* __restrict__ Wf,
                                  const float* __restrict__ asf, const float* __restrict__ adf,
                                  float* __restrict__ h, float* __restrict__ es,
                                  float* __restrict__ ed, int n) {
    int node = (int)((blockIdx.x * (long long)blockDim.x + threadIdx.x) >> 6);
    int lane = threadIdx.x & 63;
    if (node >= n) return;
    const float* xr = x + (long long)node * HID;
    float p = 0.f;
    for (int c = lane; c < HID; c += 64) p += xr[c] * Wf[c];
    #pragma unroll
    for (int o = 32; o; o >>= 1) p += __shfl_xor(p, o);
    if (lane == 0) {
        h[node] = p;
        es[node] = p * asf[0];
        ed[node] = p * adf[0];
    }
}

// ---------------- fused segment-softmax + gather-accumulate (dout=96, fp16 h) ----------------
// One wave per node. (src, logit) packed in LDS as uint2 -> one ds_read_b64 per row;
// exp fused into the accumulate loop (broadcast row => all lanes hold identical lsum,
// no shuffle reduce needed).
__global__ __launch_bounds__(256) void aggregate96_kernel(
    const unsigned* __restrict__ rs, const int* __restrict__ srcs,
    const float* __restrict__ es, const float* __restrict__ ed,
    const __half* __restrict__ h, const float* __restrict__ b,
    const float* __restrict__ res, float* __restrict__ out, int do_relu) {
    __shared__ uint2 sh[4][MAXD];
    int node = (int)((blockIdx.x * (long long)blockDim.x + threadIdx.x) >> 6);
    int lane = threadIdx.x & 63;
    int wv = threadIdx.x >> 6;
    if (node >= N_NODES) return;
    unsigned row = rs[node];
    int deg = (int)(rs[node + 1] - row);
    float edv = ed[node];
    bool single = (deg <= MAXD);   // wave-uniform

    // pass 1: segment max; stash (src, logit) packed for the single-chunk case
    float lmax = -1e30f;
    for (int j = lane; j < deg; j += 64) {
        int s = srcs[row + j];
        float v = es[s] + edv;
        v = v > 0.f ? v : NEG_SLOPE * v;
        if (single) { uint2 p; p.x = (unsigned)s; p.y = __float_as_uint(v); sh[wv][j] = p; }
        lmax = fmaxf(lmax, v);
    }
    #pragma unroll
    for (int o = 32; o; o >>= 1) lmax = fmaxf(lmax, __shfl_xor(lmax, o));

    float lsum = 0.f;
    float accx = 0.f, accy = 0.f;
    const __half2* h2 = (const __half2*)h;

    for (int base = 0; base < deg; base += MAXD) {
        int cnt = min(MAXD, deg - base);
        if (!single) {
            for (int j = lane; j < cnt; j += 64) {
                int s = srcs[row + base + j];
                float v = es[s] + edv;
                v = v > 0.f ? v : NEG_SLOPE * v;
                uint2 p; p.x = (unsigned)s; p.y = __float_as_uint(v);
                sh[wv][j] = p;   // same-wave RAW, ordered by lgkmcnt
            }
        }
        int j = 0;
        for (; j + 4 <= cnt; j += 4) {
            uint2 p0 = sh[wv][j],     p1 = sh[wv][j + 1];
            uint2 p2 = sh[wv][j + 2], p3 = sh[wv][j + 3];
            float e0 = __expf(__uint_as_float(p0.y) - lmax);
            float e1 = __expf(__uint_as_float(p1.y) - lmax);
            float e2 = __expf(__uint_as_float(p2.y) - lmax);
            float e3 = __expf(__uint_as_float(p3.y) - lmax);
            lsum += e0 + e1 + e2 + e3;
            if (lane < 48) {
                float2 v0 = __half22float2(h2[(size_t)p0.x * 48 + lane]);
                float2 v1 = __half22float2(h2[(size_t)p1.x * 48 + lane]);
                float2 v2 = __half22float2(h2[(size_t)p2.x * 48 + lane]);
                float2 v3 = __half22float2(h2[(size_t)p3.x * 48 + lane]);
                accx += e0 * v0.x + e1 * v1.x + e2 * v2.x + e3 * v3.x;
                accy += e0 * v0.y + e1 * v1.y + e2 * v2.y + e3 * v3.y;
            }
        }
        for (; j < cnt; ++j) {
            uint2 p = sh[wv][j];
            float e = __expf(__uint_as_float(p.y) - lmax);
            lsum += e;
            if (lane < 48) {
                float2 v = __half22float2(h2[(size_t)p.x * 48 + lane]);
                accx += e * v.x;
                accy += e * v.y;
            }
        }
    }

    if (lane < 48) {
        float inv = 1.f / lsum;   // lsum identical on all lanes (broadcast accumulation)
        float2 bb = ((const float2*)b)[lane];
        float vx = accx * inv + bb.x;
        float vy = accy * inv + bb.y;
        if (res) {
            float2 rr = ((const float2*)(res + (size_t)node * HID))[lane];
            vx += rr.x; vy += rr.y;
        }
        if (do_relu) { vx = fmaxf(vx, 0.f); vy = fmaxf(vy, 0.f); }
        float2 o2; o2.x = vx; o2.y = vy;
        ((float2*)(out + (size_t)node * HID))[lane] = o2;
    }
}

// ---------------- dout=1 aggregate (final layer, fp32 scalar h) ----------------
__global__ __launch_bounds__(256) void aggregate1_kernel(
    const unsigned* __restrict__ rs, const int* __restrict__ srcs,
    const float* __restrict__ es, const float* __restrict__ ed,
    const float* __restrict__ h, const float* __restrict__ b,
    float* __restrict__ out) {
    int node = (int)((blockIdx.x * (long long)blockDim.x + threadIdx.x) >> 6);
    int lane = threadIdx.x & 63;
    if (node >= N_NODES) return;
    unsigned row = rs[node];
    int deg = (int)(rs[node + 1] - row);
    float edv = ed[node];

    float lmax = -1e30f;
    for (int j = lane; j < deg; j += 64) {
        int s = srcs[row + j];
        float v = es[s] + edv;
        v = v > 0.f ? v : NEG_SLOPE * v;
        lmax = fmaxf(lmax, v);
    }
    #pragma unroll
    for (int o = 32; o; o >>= 1) lmax = fmaxf(lmax, __shfl_xor(lmax, o));

    float lsum = 0.f, acc = 0.f;
    for (int j = lane; j < deg; j += 64) {
        int s = srcs[row + j];
        float v = es[s] + edv;
        v = v > 0.f ? v : NEG_SLOPE * v;
        float ex = __expf(v - lmax);
        lsum += ex;
        acc += ex * h[s];
    }
    #pragma unroll
    for (int o = 32; o; o >>= 1) {
        lsum += __shfl_xor(lsum, o);
        acc  += __shfl_xor(acc, o);
    }
    if (lane == 0) out[node] = acc / lsum + b[0];
}

// ---------------- host-side orchestration ----------------

extern "C" void kernel_launch(void* const* d_in, const int* in_sizes, int n_in,
                              void* d_out, int out_size, void* d_ws, size_t ws_size,
                              hipStream_t stream) {
    const float* x  = (const float*)d_in[0];
    const int*   ei = (const int*)d_in[1];
    const float* W0 = (const float*)d_in[3];
    const float* as0 = (const float*)d_in[4];
    const float* ad0 = (const float*)d_in[5];
    const float* b0 = (const float*)d_in[6];
    const float* W1 = (const float*)d_in[7];
    const float* as1 = (const float*)d_in[8];
    const float* ad1 = (const float*)d_in[9];
    const float* b1 = (const float*)d_in[10];
    const float* W2 = (const float*)d_in[11];
    const float* as2 = (const float*)d_in[12];
    const float* ad2 = (const float*)d_in[13];
    const float* b2 = (const float*)d_in[14];
    const float* Wf = (const float*)d_in[15];
    const float* asf = (const float*)d_in[16];
    const float* adf = (const float*)d_in[17];
    const float* bf = (const float*)d_in[18];

    float* out = (float*)d_out;  // 50000 floats

    // workspace carve-up
    float* Hf = (float*)d_ws;                    // N*96 floats slot (fp16 h + final fp32 h)
    __half* H16 = (__half*)Hf;
    float* FA = Hf + (long long)N_NODES * HID;   // N*96
    float* FB = FA + (long long)N_NODES * HID;   // N*96
    float* ES = FB + (long long)N_NODES * HID;   // N
    float* ED = ES + N_NODES;                    // N
    unsigned* RS   = (unsigned*)(ED + N_NODES);  // N+1
    unsigned* WPTR = RS + (N_NODES + 1);         // N
    int* SRCS = (int*)(WPTR + N_NODES);          // E_TOT
    unsigned* DEG = (unsigned*)Hf;               // CSR temporaries aliased onto H slot
    unsigned* BS  = DEG + N_NODES;

    // ---- CSR build ----
    hipMemsetAsync(DEG, 0, (size_t)N_NODES * sizeof(unsigned), stream);
    hist_kernel<<<cdiv(E_TOT, 256), 256, 0, stream>>>(ei, DEG);
    scan_block_kernel<<<N_SCAN_BLOCKS, SCAN_BS, 0, stream>>>(DEG, RS, BS, N_NODES);
    scan_fix_kernel<<<cdiv(N_NODES + 1, 256), 256, 0, stream>>>(RS, BS, WPTR, N_NODES);
    {
        const int nb_e = cdiv(E_TOT, 256);
        fill_win_kernel<<<nb_e * FILL_PASSES, 256, 0, stream>>>(ei, WPTR, SRCS);
    }

    const int gemm_threads = (N_NODES / 4) * 24;   // 300000

    // ---- layer 0: x(32) -> FA(96), relu, no residual ----
    gemm_h16_kernel<<<cdiv(gemm_threads, 256), 256, 0, stream>>>(x, W0, H16, N_NODES, IN_DIM);
    scores_kernel<<<cdiv(N_NODES, 4), 256, 0, stream>>>(H16, as0, ad0, ES, ED, N_NODES);
    aggregate96_kernel<<<cdiv(N_NODES, 4), 256, 0, stream>>>(RS, SRCS, ES, ED, H16, b0, nullptr, FA, 1);

    // ---- layer 1: FA -> FB, residual FA, relu ----
    gemm_h16_kernel<<<cdiv(gemm_threads, 256), 256, 0, stream>>>(FA, W1, H16, N_NODES, HID);
    scores_kernel<<<cdiv(N_NODES, 4), 256, 0, stream>>>(H16, as1, ad1, ES, ED, N_NODES);
    aggregate96_kernel<<<cdiv(N_NODES, 4), 256, 0, stream>>>(RS, SRCS, ES, ED, H16, b1, FA, FB, 1);

    // ---- layer 2: FB -> FA, residual FB, relu ----
    gemm_h16_kernel<<<cdiv(gemm_threads, 256), 256, 0, stream>>>(FB, W2, H16, N_NODES, HID);
    scores_kernel<<<cdiv(N_NODES, 4), 256, 0, stream>>>(H16, as2, ad2, ES, ED, N_NODES);
    aggregate96_kernel<<<cdiv(N_NODES, 4), 256, 0, stream>>>(RS, SRCS, ES, ED, H16, b2, FB, FA, 1);

    // ---- final: FA -> out (dout=1), fp32 path ----
    final_proj_kernel<<<cdiv(N_NODES, 4), 256, 0, stream>>>(FA, Wf, asf, adf, Hf, ES, ED, N_NODES);
    aggregate1_kernel<<<cdiv(N_NODES, 4), 256, 0, stream>>>(RS, SRCS, ES, ED, Hf, bf, out);
}